// Round 4
// baseline (391.560 us; speedup 1.0000x reference)
//
#include <hip/hip_runtime.h>
#include <hip/hip_bf16.h>

// SplitMLP: B=128, C=16, V=32, H=64, O=4, G=10000
// v5: T3+T4 DMA ring. All prior versions (barriered LDS-share, barrier-free
// wave-per-group, group-streaming) plateaued at 120-150us / 1.4 TB/s with all
// pipes <11% busy: per-wave reg-staged loads with <=1-group lookahead give
// small, BURSTY outstanding-load queues that drain to zero at every wait.
// v5 builds the documented deep pipeline instead:
//   - weights (W1d,W1v,W2,b1) stream through a DEPTH-2 LDS slot ring filled by
//     __builtin_amdgcn_global_load_lds width=16 (no VGPR staging), jobs
//     partitioned across the block's 8 waves (2 DMA instr/wave/slot),
//   - counted s_waitcnt vmcnt(N) (never 0 mid-loop; N derived from FIFO-retire
//     op counts) so next-slot DMAs stay in flight ACROSS both barriers,
//   - W1/W2 LDS reads XOR-swizzled (byte bits[6:5] ^= bits[8:7]) via
//     inverse-swizzled DMA *source* + swizzled read (both-sides rule) to kill
//     the 16-way row-stride bank conflicts,
//   - items per-wave reg-prefetched 1 group ahead (compiler-counted waits),
//   - block = 512 thr / 8 waves = all 128 batches x NG=8 groups, grid 1250;
//     out stores: 8 groups * 16B = 128B/row/block, full-line aligned.
// Numerics identical to v0-v4 (same frag math, K-order, f32 bias adds).

typedef __bf16 v8bf __attribute__((ext_vector_type(8)));
typedef __bf16 v4bf __attribute__((ext_vector_type(4)));
typedef float  v4f  __attribute__((ext_vector_type(4)));

#define B_   128
#define C_   16
#define V_   32
#define H_   64
#define O_   4
#define G_   10000
#define NG   8        // groups per block; grid = G/NG = 1250
#define SLOT_B  14336 // slot bytes: W1d 4096 | W1v 8192 | W2 1024 | b1 1024(pad)
#define OFF_W1D 0
#define OFF_W1V 4096
#define OFF_W2  12288
#define OFF_B1  13312
#define HS_  72       // Hb stride (elems): 144B, 16B-aligned

__device__ __forceinline__ void dma16(const void* g, void* l) {
  __builtin_amdgcn_global_load_lds(
      (const __attribute__((address_space(1))) void*)g,
      (__attribute__((address_space(3))) void*)l, 16, 0, 0);
}
// byte-offset swizzle: bits[6:5] ^= bits[8:7]; involution, preserves 32B blocks
__device__ __forceinline__ int swz(int a) { return a ^ (((a >> 7) & 3) << 5); }

__device__ __forceinline__ v8bf cvt8(float4 lo, float4 hi) {
  v8bf r;
  r[0] = (__bf16)lo.x; r[1] = (__bf16)lo.y; r[2] = (__bf16)lo.z; r[3] = (__bf16)lo.w;
  r[4] = (__bf16)hi.x; r[5] = (__bf16)hi.y; r[6] = (__bf16)hi.z; r[7] = (__bf16)hi.w;
  return r;
}

__global__ __launch_bounds__(512, 4)
void splitmlp_kernel(const float* __restrict__ day,
                     const float* __restrict__ items,
                     const float* __restrict__ W1d,
                     const float* __restrict__ W1v,
                     const float* __restrict__ b1,
                     const float* __restrict__ W2,
                     const float* __restrict__ b2,
                     float* __restrict__ out) {
  __shared__ __align__(1024) char Slot[2 * SLOT_B];   // 28,672 B ring
  __shared__ __bf16 Hb[8][16 * HS_];                  // 18,432 B per-wave h^T

  const int t    = threadIdx.x;
  const int w    = t >> 6;
  const int lane = t & 63;
  const int c    = lane & 15;
  const int q    = lane >> 4;
  const int g0   = blockIdx.x * NG;
  const int row0 = w * 16;          // this wave's batch rows [row0, row0+16)

  v8bf zf;
#pragma unroll
  for (int i = 0; i < 8; ++i) zf[i] = (__bf16)0.0f;
  const v4f zero = {0.f, 0.f, 0.f, 0.f};

  // ---- DMA job decode: 14 jobs/slot, 2 per wave (waves 6,7 dup jobs 0,1) ----
  // j0-3: W1d 1KB chunks | j4-11: W1v | j12: W2 | j13: b1 (lane-clamped, linear)
  const char* jsrc[2]; size_t jstep[2]; int jlds[2];
  {
    const int jbs[2] = {w, (w + 8 < 14) ? w + 8 : w + 8 - 14};
#pragma unroll
    for (int i = 0; i < 2; ++i) {
      const int jb = jbs[i];
      const float* base; int gsb, roff, chunk;
      if (jb < 4)        { base = W1d; gsb = H_ * C_ * 4; roff = OFF_W1D; chunk = jb; }
      else if (jb < 12)  { base = W1v; gsb = H_ * V_ * 4; roff = OFF_W1V; chunk = jb - 4; }
      else if (jb == 12) { base = W2;  gsb = O_ * H_ * 4; roff = OFF_W2;  chunk = 0; }
      else               { base = b1;  gsb = H_ * 4;      roff = OFF_B1;  chunk = 0; }
      const int x = chunk * 1024 + lane * 16;
      const int soff = (jb == 13) ? ((lane < 16 ? lane : 15) * 16) : swz(x);
      jsrc[i]  = (const char*)base + (size_t)g0 * gsb + soff;
      jstep[i] = (size_t)gsb;
      jlds[i]  = roff + chunk * 1024;
    }
  }
#define ISSUE_SLOT(S) {                                          \
    char* sb_ = &Slot[((S) & 1) * SLOT_B];                       \
    dma16(jsrc[0] + (size_t)(S) * jstep[0], sb_ + jlds[0]);      \
    dma16(jsrc[1] + (size_t)(S) * jstep[1], sb_ + jlds[1]); }

  // ---- day loads (issued first; q>=2 lanes clamp addr, discarded later) ----
  float4 dA, dB;
  {
    const float* pd = day + (size_t)(row0 + c) * C_ + (q & 1) * 8;
    dA = reinterpret_cast<const float4*>(pd)[0];
    dB = reinterpret_cast<const float4*>(pd)[1];
  }

  // ---- items streaming ptr: lane(c,q) owns 8 floats of row (row0+c) ----
  // frag0 q>=2 -> items[(q-2)*8]; frag1 q<2 -> items[16+q*8] => ioff=((q+2)&3)*8
  const int ioff = ((q + 2) & 3) * 8;
  const float* pit = items + (size_t)(row0 + c) * (G_ * V_) + (size_t)g0 * V_ + ioff;
  float4 it[2][2];

  // ---- prologue (issue order fixed for vmcnt math) ----
  ISSUE_SLOT(0);                                  // slot 0 DMAs (2)
  it[0][0] = reinterpret_cast<const float4*>(pit)[0];   // items g0 (2)
  it[0][1] = reinterpret_cast<const float4*>(pit)[1];
  ISSUE_SLOT(1);                                  // slot 1 DMAs (2)
  const v8bf dayf = (q < 2) ? cvt8(dA, dB) : zf;  // compiler: counted wait

  // ---- per-lane swizzled read offsets into a slot (bytes, f32 data) ----
  const int wf0_off = (q < 2) ? (OFF_W1D + swz(c * 64 + q * 32))
                              : (OFF_W1V + swz(c * 128 + (q - 2) * 32));
  const int wf0_ms  = (q < 2) ? 1024 : 2048;      // m-tile stride (swz-invariant)
  const int wf1_off = OFF_W1V + swz(c * 128 + 64 + (q & 1) * 32); // q>=2 clamped
  const int w2_off0 = OFF_W2 + swz((c & 3) * 256 + q * 32);
  const int w2_off1 = OFF_W2 + swz((c & 3) * 256 + 128 + q * 32);

#pragma unroll
  for (int gi = 0; gi < NG; ++gi) {
    // [A] counted wait: slot(gi) DMAs are the oldest; newer-op count =
    //     steady: b2(1)+store(1)+items(2)+slotDMA(2)=6 ; edges: 4.
    if (gi == 0 || gi == NG - 1) {
      asm volatile("s_waitcnt vmcnt(4)" ::: "memory");
    } else {
      asm volatile("s_waitcnt vmcnt(6)" ::: "memory");
    }
    __builtin_amdgcn_s_barrier();           // [B] slot(gi) visible to all waves
    __builtin_amdgcn_sched_barrier(0);

    const char* sb = &Slot[(gi & 1) * SLOT_B];
    const float4 b2v = *reinterpret_cast<const float4*>(b2 + (size_t)(g0 + gi) * O_);

    // ---- W frags from LDS (f32, swizzled reads ~conflict-free) -> bf16 ----
    v8bf wf0[4], wf1[4], w2f[2];
#pragma unroll
    for (int m = 0; m < 4; ++m) {
      const char* p = sb + wf0_off + m * wf0_ms;
      wf0[m] = cvt8(*reinterpret_cast<const float4*>(p),
                    *reinterpret_cast<const float4*>(p + 16));
      const char* p1 = sb + wf1_off + m * 2048;
      const v8bf x1 = cvt8(*reinterpret_cast<const float4*>(p1),
                           *reinterpret_cast<const float4*>(p1 + 16));
      wf1[m] = (q < 2) ? x1 : zf;
    }
    {
      const char* pa = sb + w2_off0;
      const char* pb = sb + w2_off1;
      const v8bf a0 = cvt8(*reinterpret_cast<const float4*>(pa),
                           *reinterpret_cast<const float4*>(pa + 16));
      const v8bf a1 = cvt8(*reinterpret_cast<const float4*>(pb),
                           *reinterpret_cast<const float4*>(pb + 16));
      w2f[0] = (c < O_) ? a0 : zf;
      w2f[1] = (c < O_) ? a1 : zf;
    }

    // ---- B-frags: day regs + items regs ----
    const v8bf icf = cvt8(it[gi & 1][0], it[gi & 1][1]);
    const v8bf blv = (q < 2) ? dayf : icf;
    const v8bf bhv = (q < 2) ? icf : zf;

    // ---- fc1: h^T[64][16 rows] ----
    v4f acc[4];
#pragma unroll
    for (int m = 0; m < 4; ++m) acc[m] = zero;
#pragma unroll
    for (int m = 0; m < 4; ++m) {
      acc[m] = __builtin_amdgcn_mfma_f32_16x16x32_bf16(wf0[m], blv, acc[m], 0, 0, 0);
      acc[m] = __builtin_amdgcn_mfma_f32_16x16x32_bf16(wf1[m], bhv, acc[m], 0, 0, 0);
    }

    // ---- epilogue: +b1 (f32 from LDS), ReLU, pack -> wave-private Hb ----
#pragma unroll
    for (int m = 0; m < 4; ++m) {
      const float4 bb = *reinterpret_cast<const float4*>(sb + OFF_B1 + m * 64 + q * 16);
      v4bf hv;
      hv[0] = (__bf16)fmaxf(acc[m][0] + bb.x, 0.f);
      hv[1] = (__bf16)fmaxf(acc[m][1] + bb.y, 0.f);
      hv[2] = (__bf16)fmaxf(acc[m][2] + bb.z, 0.f);
      hv[3] = (__bf16)fmaxf(acc[m][3] + bb.w, 0.f);
      *reinterpret_cast<v4bf*>(&Hb[w][c * HS_ + m * 16 + q * 4]) = hv;
    }

    // ---- fc2: y^T = W2(pad16) @ h^T ----
    v4f y = zero;
#pragma unroll
    for (int kt = 0; kt < 2; ++kt) {
      const v8bf hf = *reinterpret_cast<const v8bf*>(&Hb[w][c * HS_ + kt * 32 + q * 8]);
      y = __builtin_amdgcn_mfma_f32_16x16x32_bf16(w2f[kt], hf, y, 0, 0, 0);
    }

    // ---- store (q==0 lanes hold o=0..3 for row row0+c) ----
    if (q == 0) {
      float4 o;
      o.x = y[0] + b2v.x;
      o.y = y[1] + b2v.y;
      o.z = y[2] + b2v.z;
      o.w = y[3] + b2v.w;
      *reinterpret_cast<float4*>(out + (size_t)(row0 + c) * (G_ * O_) +
                                 (size_t)(g0 + gi) * O_) = o;
    }

    // [D] items prefetch for gi+1 (stays outstanding across barriers)
    if (gi < NG - 1) {
      const float* pn = pit + (size_t)(gi + 1) * V_;
      it[(gi + 1) & 1][0] = reinterpret_cast<const float4*>(pn)[0];
      it[(gi + 1) & 1][1] = reinterpret_cast<const float4*>(pn)[1];
    }

    __builtin_amdgcn_s_barrier();   // [E0] all waves done reading slot(gi)
    if (gi < NG - 2) ISSUE_SLOT(gi + 2);   // [E] overwrite phys slot gi&1
  }
#undef ISSUE_SLOT
}

extern "C" void kernel_launch(void* const* d_in, const int* in_sizes, int n_in,
                              void* d_out, int out_size, void* d_ws, size_t ws_size,
                              hipStream_t stream) {
  const float* day   = (const float*)d_in[0];
  const float* items = (const float*)d_in[1];
  const float* W1d   = (const float*)d_in[2];
  const float* W1v   = (const float*)d_in[3];
  const float* b1    = (const float*)d_in[4];
  const float* W2    = (const float*)d_in[5];
  const float* b2    = (const float*)d_in[6];
  float* out = (float*)d_out;
  splitmlp_kernel<<<G_ / NG, 512, 0, stream>>>(day, items, W1d, W1v, b1, W2, b2, out);
}